// Round 6
// baseline (110.596 us; speedup 1.0000x reference)
//
#include <hip/hip_runtime.h>
#include <hip/hip_bf16.h>
#include <stdint.h>

#define BATCH 32
#define CIN   256
#define COUT  256
#define HW    3136   // 56*56
#define NPAD  3200   // pad HW to multiple of 128

typedef short bf16x8 __attribute__((ext_vector_type(8)));
typedef float f32x4  __attribute__((ext_vector_type(4)));

__device__ __forceinline__ unsigned short f2bf(float f) {
    unsigned u = __float_as_uint(f);
    u += 0x7fffu + ((u >> 16) & 1u);   // round-to-nearest-even
    return (unsigned short)(u >> 16);
}

// ---------------- K0: fold BN2 into pw weights; zero pwmax -----------------
__global__ __launch_bounds__(256) void prep_kernel(
        const float* __restrict__ pw_w, const float* __restrict__ pw_b,
        const float* __restrict__ g2, const float* __restrict__ be2,
        const float* __restrict__ mu2, const float* __restrict__ va2,
        unsigned short* __restrict__ Wp, float* __restrict__ b2,
        unsigned* __restrict__ pwmax) {
    int o = blockIdx.x;
    int t = threadIdx.x;
    float inv2 = g2[o] * rsqrtf(va2[o] + 1e-5f);
    Wp[o * CIN + t] = f2bf(pw_w[o * CIN + t] * inv2);
    if (t == 0) b2[o] = pw_b[o] * inv2 + be2[o] - mu2[o] * inv2;
    int idx = blockIdx.x * 256 + t;
    if (idx < BATCH * COUT) pwmax[idx] = 0u;
}

// ---------------- K1: depthwise 3x3 + BN1 + ReLU -> y bf16 (UNCUT) --------
// Column-sweep: one WAVE per plane, lane = column. Lane c loads x[q][c]
// (wave load = 224B contiguous); horizontal taps via shfl of current row;
// vertical taps via rolling accumulators:
//   out[r] = t(r-1) + m(r) + btm(r+1),  t/m/btm = row's {top,mid,bot} terms.
// No LDS, no barriers, ~30 VGPR, 56 independent row loads -> deep pipeline.
__global__ __launch_bounds__(256) void dw_kernel(
        const float* __restrict__ x, const float* __restrict__ dww,
        const float* __restrict__ dwb,
        const float* __restrict__ g1, const float* __restrict__ be1,
        const float* __restrict__ mu1, const float* __restrict__ va1,
        unsigned short* __restrict__ y, float* __restrict__ dwmax) {
    int lane = threadIdx.x & 63;
    int wid  = threadIdx.x >> 6;
    int plane = blockIdx.x * 4 + wid;      // 2048 blocks x 4 planes
    int c = plane & 255;

    int col = lane < 56 ? lane : 55;       // clamp inactive lanes
    bool active = lane < 56;
    const float* xp = x + (size_t)plane * HW + col;
    unsigned short* yp = y + (size_t)plane * NPAD + col;

    float w00 = dww[c*9+0], w01 = dww[c*9+1], w02 = dww[c*9+2];
    float w10 = dww[c*9+3], w11 = dww[c*9+4], w12 = dww[c*9+5];
    float w20 = dww[c*9+6], w21 = dww[c*9+7], w22 = dww[c*9+8];
    float inv = g1[c] * rsqrtf(va1[c] + 1e-5f);
    float b0  = dwb[c] * inv + (be1[c] - mu1[c] * inv);

    float A = 0.f;   // partial of out[q-1]: t(q-2)+m(q-1)
    float B = 0.f;   // partial of out[q]:   t(q-1)
    float lmax = 0.f;

#pragma unroll
    for (int q = 0; q < 56; ++q) {
        float xv = xp[q * 56];
        float xl = __shfl_up(xv, 1, 64);
        float xr = __shfl_down(xv, 1, 64);
        if (lane == 0)  xl = 0.f;
        if (lane >= 55) xr = 0.f;
        // finalize out[q-1]
        float outv = fmaf(xl, w20, fmaf(xv, w21, fmaf(xr, w22, A)));
        // roll accumulators
        A = fmaf(xl, w10, fmaf(xv, w11, fmaf(xr, w12, B)));
        B = fmaf(xl, w00, fmaf(xv, w01, xr * w02));
        if (q >= 1) {
            float v = fmaxf(fmaf(outv, inv, b0), 0.f);
            if (active) {
                lmax = fmaxf(lmax, v);
                yp[(q - 1) * 56] = f2bf(v);
            }
        }
    }
    {   // out[55] = A (btm(56)=0)
        float v = fmaxf(fmaf(A, inv, b0), 0.f);
        if (active) {
            lmax = fmaxf(lmax, v);
            yp[55 * 56] = f2bf(v);
        }
    }
    // wave max reduce -> dwmax[plane] (wave exclusively owns plane)
    for (int off = 32; off >= 1; off >>= 1)
        lmax = fmaxf(lmax, __shfl_xor(lmax, off, 64));
    if (lane == 0) dwmax[plane] = lmax;
    // zero pad cols HW..NPAD (64 shorts = 128B)
    if (lane < 8) *(uint4*)(y + (size_t)plane * NPAD + HW + lane * 8)
        = make_uint4(0, 0, 0, 0);
}

// ---------------- K2: pointwise GEMM (bf16 MFMA) + dw-cut + BN2 + ReLU ----
// Z_b (O x HW) = W' (O x C) * Y_b(C x HW), rows k with dwmax[b,k] < 4 -> 0.
__global__ __launch_bounds__(256) void pw_kernel(
        const unsigned short* __restrict__ y, const unsigned short* __restrict__ Wp,
        const float* __restrict__ b2, const float* __restrict__ dwm,
        float* __restrict__ z, unsigned* __restrict__ pwmax) {
    __shared__ __align__(16) unsigned short Al[128 * 64];  // [m][k], chunk-swizzled by (m&7)
    __shared__ __align__(16) unsigned short Bl[128 * 64];  // [n][k], chunk-swizzled by ((n>>2)&7)

    int bid0 = blockIdx.x;                      // 1600
    int bid = (bid0 & 7) * 200 + (bid0 >> 3);   // XCD-pairing swizzle (bijective)
    int mt = bid & 1;
    int rest = bid >> 1;
    int nt = rest % 25;
    int b = rest / 25;
    int m0 = mt * 128, n0 = nt * 128;

    int tid = threadIdx.x;
    int lane = tid & 63, wid = tid >> 6;
    int wm = (wid & 1) * 64, wn = (wid >> 1) * 64;
    int l15 = lane & 15, l4 = lane >> 4;

    const unsigned short* yb = y + (size_t)b * CIN * NPAD;
    const float* dwb_ = dwm + b * 256;

    // per-thread staging maps
    int am[4], acch[4];
    const unsigned short* asrc[4];
#pragma unroll
    for (int i = 0; i < 4; ++i) {
        int s = i * 256 + tid;
        int m = s >> 3, cch = s & 7, dch = cch ^ (m & 7);
        am[i] = m; acch[i] = cch;
        asrc[i] = Wp + (size_t)(m0 + m) * CIN + dch * 8;
    }
    int bq[2], bnq[2];
    const unsigned short* bsrc[2];
#pragma unroll
    for (int i = 0; i < 2; ++i) {
        int u = tid + i * 256;
        bq[i] = u >> 5; bnq[i] = u & 31;
        bsrc[i] = yb + (size_t)(bq[i] * 4) * NPAD + n0 + bnq[i] * 4;
    }

    uint4 areg[4];
    uint2 breg[2][4];
    float4 fl[2];
#pragma unroll
    for (int i = 0; i < 4; ++i) areg[i] = *(const uint4*)(asrc[i]);
#pragma unroll
    for (int i = 0; i < 2; ++i) {
#pragma unroll
        for (int r = 0; r < 4; ++r) breg[i][r] = *(const uint2*)(bsrc[i] + r * NPAD);
        fl[i] = *(const float4*)(dwb_ + bq[i] * 4);
    }

    f32x4 acc[4][4];
#pragma unroll
    for (int mf = 0; mf < 4; ++mf)
#pragma unroll
        for (int nf = 0; nf < 4; ++nf) acc[mf][nf] = {0.f, 0.f, 0.f, 0.f};

#pragma unroll
    for (int kk = 0; kk < 4; ++kk) {
        __builtin_amdgcn_s_barrier();      // all waves done reading LDS (iter 0: no-op)
        __builtin_amdgcn_sched_barrier(0);
        // A: store prefetched regs (swizzled slots)
#pragma unroll
        for (int i = 0; i < 4; ++i)
            *(uint4*)((char*)Al + am[i] * 128 + acch[i] * 16) = areg[i];
        // B: apply dw-cut mask, pack transpose from regs, store (swizzled)
#pragma unroll
        for (int i = 0; i < 2; ++i) {
            unsigned mk0 = fl[i].x >= 4.0f ? 0xffffffffu : 0u;
            unsigned mk1 = fl[i].y >= 4.0f ? 0xffffffffu : 0u;
            unsigned mk2 = fl[i].z >= 4.0f ? 0xffffffffu : 0u;
            unsigned mk3 = fl[i].w >= 4.0f ? 0xffffffffu : 0u;
            uint2 r0 = breg[i][0], r1 = breg[i][1], r2 = breg[i][2], r3 = breg[i][3];
            r0.x &= mk0; r0.y &= mk0; r1.x &= mk1; r1.y &= mk1;
            r2.x &= mk2; r2.y &= mk2; r3.x &= mk3; r3.y &= mk3;
            int q = bq[i], nq = bnq[i];
#pragma unroll
            for (int i2 = 0; i2 < 4; ++i2) {
                unsigned x0 = (i2 & 2) ? r0.y : r0.x;
                unsigned x1 = (i2 & 2) ? r1.y : r1.x;
                unsigned x2 = (i2 & 2) ? r2.y : r2.x;
                unsigned x3 = (i2 & 2) ? r3.y : r3.x;
                if (i2 & 1) { x0 >>= 16; x2 >>= 16; }
                else        { x0 &= 0xffffu; x2 &= 0xffffu; }
                unsigned px = (i2 & 1) ? (x0 | (x1 & 0xffff0000u))
                                       : (x0 | (x1 << 16));
                unsigned py = (i2 & 1) ? (x2 | (x3 & 0xffff0000u))
                                       : (x2 | (x3 << 16));
                int nloc = nq * 4 + i2;
                int sb = nloc * 128 + (((q >> 1) ^ ((nloc >> 2) & 7)) << 4) + ((q & 1) << 3);
                *(uint2*)((char*)Bl + sb) = make_uint2(px, py);
            }
        }
        // prefetch next K-step into regs (stays in flight across the barrier)
        if (kk < 3) {
#pragma unroll
            for (int i = 0; i < 4; ++i)
                areg[i] = *(const uint4*)(asrc[i] + (kk + 1) * 64);
#pragma unroll
            for (int i = 0; i < 2; ++i) {
#pragma unroll
                for (int r = 0; r < 4; ++r)
                    breg[i][r] = *(const uint2*)(bsrc[i] + (size_t)(kk + 1) * 64 * NPAD + r * NPAD);
                fl[i] = *(const float4*)(dwb_ + (kk + 1) * 64 + bq[i] * 4);
            }
        }
        asm volatile("s_waitcnt lgkmcnt(0)" ::: "memory");  // LDS writes visible; vmcnt NOT drained
        __builtin_amdgcn_s_barrier();
        __builtin_amdgcn_sched_barrier(0);
        // compute this K-step: 2 halves of K=32
#pragma unroll
        for (int h = 0; h < 2; ++h) {
            bf16x8 af[4], bfr[4];
            int cc = h * 4 + l4;
#pragma unroll
            for (int mf = 0; mf < 4; ++mf) {
                int m = wm + mf * 16 + l15;
                af[mf] = *(const bf16x8*)((const char*)Al + m * 128 + ((cc ^ (m & 7)) << 4));
            }
#pragma unroll
            for (int nf = 0; nf < 4; ++nf) {
                int n = wn + nf * 16 + l15;
                bfr[nf] = *(const bf16x8*)((const char*)Bl + n * 128 + ((cc ^ ((n >> 2) & 7)) << 4));
            }
#pragma unroll
            for (int mf = 0; mf < 4; ++mf)
#pragma unroll
                for (int nf = 0; nf < 4; ++nf)
                    acc[mf][nf] = __builtin_amdgcn_mfma_f32_16x16x32_bf16(
                        af[mf], bfr[nf], acc[mf][nf], 0, 0, 0);
        }
    }

    // epilogue: bias + relu + store + per-o-row plane max (atomic)
    float* zb = z + (size_t)b * COUT * HW;
#pragma unroll
    for (int mf = 0; mf < 4; ++mf) {
        int obase = m0 + wm + mf * 16 + l4 * 4;
        float bb0 = b2[obase + 0], bb1 = b2[obase + 1];
        float bb2v = b2[obase + 2], bb3 = b2[obase + 3];
        float rmax[4] = {0.f, 0.f, 0.f, 0.f};
#pragma unroll
        for (int nf = 0; nf < 4; ++nf) {
            int n = n0 + wn + nf * 16 + l15;
            bool valid = (n < HW);
            float v0 = fmaxf(acc[mf][nf][0] + bb0, 0.f);
            float v1 = fmaxf(acc[mf][nf][1] + bb1, 0.f);
            float v2 = fmaxf(acc[mf][nf][2] + bb2v, 0.f);
            float v3 = fmaxf(acc[mf][nf][3] + bb3, 0.f);
            if (valid) {
                zb[(size_t)(obase + 0) * HW + n] = v0;
                zb[(size_t)(obase + 1) * HW + n] = v1;
                zb[(size_t)(obase + 2) * HW + n] = v2;
                zb[(size_t)(obase + 3) * HW + n] = v3;
                rmax[0] = fmaxf(rmax[0], v0);
                rmax[1] = fmaxf(rmax[1], v1);
                rmax[2] = fmaxf(rmax[2], v2);
                rmax[3] = fmaxf(rmax[3], v3);
            }
        }
#pragma unroll
        for (int r = 0; r < 4; ++r) {
            float v = rmax[r];
            v = fmaxf(v, __shfl_xor(v, 1, 64));
            v = fmaxf(v, __shfl_xor(v, 2, 64));
            v = fmaxf(v, __shfl_xor(v, 4, 64));
            v = fmaxf(v, __shfl_xor(v, 8, 64));
            if (l15 == 0)
                atomicMax(&pwmax[b * COUT + obase + r], __float_as_uint(v));
        }
    }
}

// ---------------- K3: apply pointwise cut ---------------------------------
__global__ __launch_bounds__(256) void cut_kernel(const unsigned* __restrict__ pwmax,
                                                  float* __restrict__ z) {
    int base = blockIdx.x * 8;
#pragma unroll
    for (int j = 0; j < 8; ++j) {
        int bo = base + j;
        if (__uint_as_float(pwmax[bo]) >= 1e-3f) continue;
        float4* zp = (float4*)(z + (size_t)bo * HW);
        for (int i = threadIdx.x; i < HW / 4; i += 256)
            zp[i] = make_float4(0.f, 0.f, 0.f, 0.f);
    }
}

extern "C" void kernel_launch(void* const* d_in, const int* in_sizes, int n_in,
                              void* d_out, int out_size, void* d_ws, size_t ws_size,
                              hipStream_t stream) {
    const float* x   = (const float*)d_in[0];
    const float* dww = (const float*)d_in[1];
    const float* dwb = (const float*)d_in[2];
    const float* g1  = (const float*)d_in[3];
    const float* be1 = (const float*)d_in[4];
    const float* mu1 = (const float*)d_in[5];
    const float* va1 = (const float*)d_in[6];
    const float* pww = (const float*)d_in[7];
    const float* pwb = (const float*)d_in[8];
    const float* g2  = (const float*)d_in[9];
    const float* be2 = (const float*)d_in[10];
    const float* mu2 = (const float*)d_in[11];
    const float* va2 = (const float*)d_in[12];
    float* z = (float*)d_out;

    char* ws = (char*)d_ws;
    const size_t Y_BYTES = (size_t)BATCH * CIN * NPAD * 2;  // 52,428,800
    unsigned short* y  = (unsigned short*)ws;
    unsigned short* Wp = (unsigned short*)(ws + Y_BYTES);
    float* b2          = (float*)(ws + Y_BYTES + 131072);
    unsigned* pwmax    = (unsigned*)(ws + Y_BYTES + 131072 + 1024);
    float* dwmax       = (float*)(ws + Y_BYTES + 131072 + 1024 + 32768);

    prep_kernel<<<256, 256, 0, stream>>>(pww, pwb, g2, be2, mu2, va2, Wp, b2, pwmax);
    dw_kernel<<<2048, 256, 0, stream>>>(x, dww, dwb, g1, be1, mu1, va1, y, dwmax);
    pw_kernel<<<1600, 256, 0, stream>>>(y, Wp, b2, dwmax, z, pwmax);
    cut_kernel<<<BATCH * COUT / 8, 256, 0, stream>>>(pwmax, z);
}

// Round 7
// 100.777 us; speedup vs baseline: 1.0974x; 1.0974x over previous
//
#include <hip/hip_runtime.h>
#include <hip/hip_bf16.h>
#include <stdint.h>

#define BATCH 32
#define CIN   256
#define COUT  256
#define HW    3136   // 56*56
#define NPAD  3200   // pad HW to multiple of 128

#define AS1 __attribute__((address_space(1)))
#define AS3 __attribute__((address_space(3)))

typedef short bf16x8 __attribute__((ext_vector_type(8)));
typedef float f32x4  __attribute__((ext_vector_type(4)));

__device__ __forceinline__ unsigned short f2bf(float f) {
    unsigned u = __float_as_uint(f);
    u += 0x7fffu + ((u >> 16) & 1u);   // round-to-nearest-even
    return (unsigned short)(u >> 16);
}

// ---------------- K0: fold BN2 into pw weights; zero pwmax -----------------
__global__ __launch_bounds__(256) void prep_kernel(
        const float* __restrict__ pw_w, const float* __restrict__ pw_b,
        const float* __restrict__ g2, const float* __restrict__ be2,
        const float* __restrict__ mu2, const float* __restrict__ va2,
        unsigned short* __restrict__ Wp, float* __restrict__ b2,
        unsigned* __restrict__ pwmax) {
    int o = blockIdx.x;
    int t = threadIdx.x;
    float inv2 = g2[o] * rsqrtf(va2[o] + 1e-5f);
    Wp[o * CIN + t] = f2bf(pw_w[o * CIN + t] * inv2);
    if (t == 0) b2[o] = pw_b[o] * inv2 + be2[o] - mu2[o] * inv2;
    int idx = blockIdx.x * 256 + t;
    if (idx < BATCH * COUT) pwmax[idx] = 0u;
}

// ---------------- K1: depthwise 3x3 + BN1 + ReLU -> y bf16 (UNCUT) --------
// Wave-per-plane. Stage whole 12.5KB plane into wave-private LDS via async
// global_load_lds (13 issues, deep DMA queue), own-wave vmcnt(0), no barrier.
// Then column-sweep from LDS: lane=col, rolling accumulators over row PAIRS,
// per-lane pre-zeroed edge weights (no per-row masks).
__global__ __launch_bounds__(256) void dw_kernel(
        const float* __restrict__ x, const float* __restrict__ dww,
        const float* __restrict__ dwb,
        const float* __restrict__ g1, const float* __restrict__ be1,
        const float* __restrict__ mu1, const float* __restrict__ va1,
        unsigned short* __restrict__ y, float* __restrict__ dwmax) {
    __shared__ float xs[4 * 3136];     // 50,176 B -> 3 blocks/CU
    int tid  = threadIdx.x;
    int lane = tid & 63, wid = tid >> 6;
    int plane = blockIdx.x * 4 + wid;  // 2048 blocks x 4 planes
    int c = plane & 255;

    const float* xp = x + (size_t)plane * HW;
    float* xw = xs + wid * 3136;

    // async stage: 12 x 16B-per-lane (1KB/issue) + 1 x 4B tail (256B)
#pragma unroll
    for (int i = 0; i < 12; ++i)
        __builtin_amdgcn_global_load_lds(
            (const AS1 void*)(xp + i * 256 + lane * 4),
            (AS3 void*)(xw + i * 256), 16, 0, 0);
    __builtin_amdgcn_global_load_lds(
        (const AS1 void*)(xp + 3072 + lane),
        (AS3 void*)(xw + 3072), 4, 0, 0);

    // scalars while DMA in flight
    float w00 = dww[c*9+0], w01 = dww[c*9+1], w02 = dww[c*9+2];
    float w10 = dww[c*9+3], w11 = dww[c*9+4], w12 = dww[c*9+5];
    float w20 = dww[c*9+6], w21 = dww[c*9+7], w22 = dww[c*9+8];
    float inv = g1[c] * rsqrtf(va1[c] + 1e-5f);
    float b0  = dwb[c] * inv + (be1[c] - mu1[c] * inv);

    int  col    = lane < 56 ? lane : 55;
    bool active = lane < 56;
    if (lane == 0)  { w00 = 0.f; w10 = 0.f; w20 = 0.f; }   // left edge
    if (lane >= 55) { w02 = 0.f; w12 = 0.f; w22 = 0.f; }   // right edge
    int il = (lane == 0) ? 0 : col - 1;
    int ir = (col == 55) ? 55 : col + 1;

    asm volatile("s_waitcnt vmcnt(0)" ::: "memory");   // own DMA done
    __builtin_amdgcn_sched_barrier(0);

    const float* xb = xw;              // wave-private plane
    unsigned short* yp = y + (size_t)plane * NPAD + col;

    float A = 0.f;    // T(q-2)+M(q-1)
    float Bv = 0.f;   // T(q-1)
    float lmax = 0.f;
#pragma unroll
    for (int q = 0; q < 56; q += 2) {
        float l0 = xb[q*56 + il],      c0 = xb[q*56 + col],      r0 = xb[q*56 + ir];
        float l1 = xb[(q+1)*56 + il],  c1 = xb[(q+1)*56 + col],  r1 = xb[(q+1)*56 + ir];
        // out[q-1] = A + Bot(q)
        if (q > 0) {
            float o0 = fmaf(l0, w20, fmaf(c0, w21, fmaf(r0, w22, A)));
            float v = fmaxf(fmaf(o0, inv, b0), 0.f);
            if (active) { lmax = fmaxf(lmax, v); yp[(q-1)*56] = f2bf(v); }
        }
        // out[q] = Bv + Mid(q) + Bot(q+1)
        {
            float o1 = fmaf(l0, w10, fmaf(c0, w11, fmaf(r0, w12,
                       fmaf(l1, w20, fmaf(c1, w21, fmaf(r1, w22, Bv))))));
            float v = fmaxf(fmaf(o1, inv, b0), 0.f);
            if (active) { lmax = fmaxf(lmax, v); yp[q*56] = f2bf(v); }
        }
        // roll: A' = T(q) + M(q+1); Bv' = T(q+1)
        float top0 = fmaf(l0, w00, fmaf(c0, w01, r0 * w02));
        A  = fmaf(l1, w10, fmaf(c1, w11, fmaf(r1, w12, top0)));
        Bv = fmaf(l1, w00, fmaf(c1, w01, r1 * w02));
    }
    {   // out[55] = A (Bot(56)=0)
        float v = fmaxf(fmaf(A, inv, b0), 0.f);
        if (active) { lmax = fmaxf(lmax, v); yp[55*56] = f2bf(v); }
    }
    // wave max reduce -> dwmax[plane]
    for (int off = 32; off >= 1; off >>= 1)
        lmax = fmaxf(lmax, __shfl_xor(lmax, off, 64));
    if (lane == 0) dwmax[plane] = lmax;
    // zero pad cols HW..NPAD (128B)
    if (lane < 8) *(uint4*)(y + (size_t)plane * NPAD + HW + lane * 8)
        = make_uint4(0, 0, 0, 0);
}

// ---------------- K2: pointwise GEMM (bf16 MFMA) + dw-cut + BN2 + ReLU ----
// Z_b (O x HW) = W' (O x C) * Y_b(C x HW), rows k with dwmax[b,k] < 4 -> 0.
// Full-MLP structure: A (128x256, 64KB LDS) staged entirely in prologue via
// 16 pre-swizzled global_load_lds; ALL B/fl loads (40) issued to regs in
// pinned order; consumed with counted vmcnt((3-kk)*10). Bl single 16KB buf.
__global__ __launch_bounds__(256, 2) void pw_kernel(
        const unsigned short* __restrict__ y, const unsigned short* __restrict__ Wp,
        const float* __restrict__ b2, const float* __restrict__ dwm,
        float* __restrict__ z, unsigned* __restrict__ pwmax) {
    __shared__ __align__(16) unsigned short Al[128 * 256];  // 64KB, per-kstep chunk-swizzled by (m&7)
    __shared__ __align__(16) unsigned short Bl[128 * 64];   // 16KB, chunk-swizzled by ((n>>2)&7)

    int bid0 = blockIdx.x;                      // 1600
    int bid = (bid0 & 7) * 200 + (bid0 >> 3);   // XCD-pairing swizzle (bijective)
    int mt = bid & 1;
    int rest = bid >> 1;
    int nt = rest % 25;
    int b = rest / 25;
    int m0 = mt * 128, n0 = nt * 128;

    int tid = threadIdx.x;
    int lane = tid & 63, wid = tid >> 6;
    int wm = (wid & 1) * 64, wn = (wid >> 1) * 64;
    int l15 = lane & 15, l4 = lane >> 4;

    const unsigned short* yb = y + (size_t)b * CIN * NPAD;
    const float* dwb_ = dwm + b * 256;

    // A staging map (per kstep sub-tile): slot s = ii*256 + wid*64 + lane;
    // m = s>>3, cch = s&7, dch = cch^(m&7); HW writes ldsbase + lane*16.
    const unsigned short* agsrc[4];
#pragma unroll
    for (int ii = 0; ii < 4; ++ii) {
        int s = ii * 256 + wid * 64 + lane;
        int m = s >> 3, cch = s & 7, dch = cch ^ (m & 7);
        agsrc[ii] = Wp + (size_t)(m0 + m) * CIN + dch * 8;
    }
    int bq[2], bnq[2];
    const unsigned short* bsrc[2];
#pragma unroll
    for (int i = 0; i < 2; ++i) {
        int u = tid + i * 256;
        bq[i] = u >> 5; bnq[i] = u & 31;
        bsrc[i] = yb + (size_t)(bq[i] * 4) * NPAD + n0 + bnq[i] * 4;
    }

    // ---- prologue: issue EVERYTHING (order pinned; 56 loads in flight) ----
#pragma unroll
    for (int ks = 0; ks < 4; ++ks)
#pragma unroll
        for (int ii = 0; ii < 4; ++ii)
            __builtin_amdgcn_global_load_lds(
                (const AS1 void*)(agsrc[ii] + ks * 64),
                (AS3 void*)((char*)Al + ks * 16384 + ii * 4096 + wid * 1024),
                16, 0, 0);
    __builtin_amdgcn_sched_barrier(0);

    uint2 breg[4][2][4];
    float4 fl[4][2];
#pragma unroll
    for (int kk = 0; kk < 4; ++kk) {
#pragma unroll
        for (int i = 0; i < 2; ++i)
#pragma unroll
            for (int r = 0; r < 4; ++r)
                breg[kk][i][r] = *(const uint2*)(bsrc[i] + (size_t)kk * 64 * NPAD + r * NPAD);
#pragma unroll
        for (int i = 0; i < 2; ++i)
            fl[kk][i] = *(const float4*)(dwb_ + kk * 64 + bq[i] * 4);
        __builtin_amdgcn_sched_barrier(0);
    }

    f32x4 acc[4][4];
#pragma unroll
    for (int mf = 0; mf < 4; ++mf)
#pragma unroll
        for (int nf = 0; nf < 4; ++nf) acc[mf][nf] = {0.f, 0.f, 0.f, 0.f};

    // ---- main loop: counted vmcnt, never drained early ----
#pragma unroll
    for (int kk = 0; kk < 4; ++kk) {
        if (kk == 0) asm volatile("s_waitcnt vmcnt(30)" ::: "memory");
        if (kk == 1) asm volatile("s_waitcnt vmcnt(20)" ::: "memory");
        if (kk == 2) asm volatile("s_waitcnt vmcnt(10)" ::: "memory");
        if (kk == 3) asm volatile("s_waitcnt vmcnt(0)"  ::: "memory");
        __builtin_amdgcn_sched_barrier(0);
        // pack B(kk): dw-cut mask + transpose -> Bl (swizzled)
#pragma unroll
        for (int i = 0; i < 2; ++i) {
            unsigned mk0 = fl[kk][i].x >= 4.0f ? 0xffffffffu : 0u;
            unsigned mk1 = fl[kk][i].y >= 4.0f ? 0xffffffffu : 0u;
            unsigned mk2 = fl[kk][i].z >= 4.0f ? 0xffffffffu : 0u;
            unsigned mk3 = fl[kk][i].w >= 4.0f ? 0xffffffffu : 0u;
            uint2 r0 = breg[kk][i][0], r1 = breg[kk][i][1];
            uint2 r2 = breg[kk][i][2], r3 = breg[kk][i][3];
            r0.x &= mk0; r0.y &= mk0; r1.x &= mk1; r1.y &= mk1;
            r2.x &= mk2; r2.y &= mk2; r3.x &= mk3; r3.y &= mk3;
            int q = bq[i], nq = bnq[i];
#pragma unroll
            for (int i2 = 0; i2 < 4; ++i2) {
                unsigned x0 = (i2 & 2) ? r0.y : r0.x;
                unsigned x1 = (i2 & 2) ? r1.y : r1.x;
                unsigned x2 = (i2 & 2) ? r2.y : r2.x;
                unsigned x3 = (i2 & 2) ? r3.y : r3.x;
                if (i2 & 1) { x0 >>= 16; x2 >>= 16; }
                else        { x0 &= 0xffffu; x2 &= 0xffffu; }
                unsigned px = (i2 & 1) ? (x0 | (x1 & 0xffff0000u))
                                       : (x0 | (x1 << 16));
                unsigned py = (i2 & 1) ? (x2 | (x3 & 0xffff0000u))
                                       : (x2 | (x3 << 16));
                int nloc = nq * 4 + i2;
                int sb = nloc * 128 + (((q >> 1) ^ ((nloc >> 2) & 7)) << 4) + ((q & 1) << 3);
                *(uint2*)((char*)Bl + sb) = make_uint2(px, py);
            }
        }
        asm volatile("s_waitcnt lgkmcnt(0)" ::: "memory");
        __builtin_amdgcn_s_barrier();          // Bl + (kk==0: A) visible
        __builtin_amdgcn_sched_barrier(0);
        // MFMA: 2 halves of K=32, A from per-kstep region of Al
#pragma unroll
        for (int h = 0; h < 2; ++h) {
            bf16x8 af[4], bfr[4];
            int cc = h * 4 + l4;
#pragma unroll
            for (int mf = 0; mf < 4; ++mf) {
                int m = wm + mf * 16 + l15;
                af[mf] = *(const bf16x8*)((const char*)Al + kk * 16384
                             + m * 128 + ((cc ^ (m & 7)) << 4));
            }
#pragma unroll
            for (int nf = 0; nf < 4; ++nf) {
                int n = wn + nf * 16 + l15;
                bfr[nf] = *(const bf16x8*)((const char*)Bl + n * 128
                             + ((cc ^ ((n >> 2) & 7)) << 4));
            }
#pragma unroll
            for (int mf = 0; mf < 4; ++mf)
#pragma unroll
                for (int nf = 0; nf < 4; ++nf)
                    acc[mf][nf] = __builtin_amdgcn_mfma_f32_16x16x32_bf16(
                        af[mf], bfr[nf], acc[mf][nf], 0, 0, 0);
        }
        __builtin_amdgcn_s_barrier();          // all reads done before next pack
    }

    // epilogue: bias + relu + store + per-o-row plane max (atomic)
    float* zb = z + (size_t)b * COUT * HW;
#pragma unroll
    for (int mf = 0; mf < 4; ++mf) {
        int obase = m0 + wm + mf * 16 + l4 * 4;
        float bb0 = b2[obase + 0], bb1 = b2[obase + 1];
        float bb2v = b2[obase + 2], bb3 = b2[obase + 3];
        float rmax[4] = {0.f, 0.f, 0.f, 0.f};
#pragma unroll
        for (int nf = 0; nf < 4; ++nf) {
            int n = n0 + wn + nf * 16 + l15;
            bool valid = (n < HW);
            float v0 = fmaxf(acc[mf][nf][0] + bb0, 0.f);
            float v1 = fmaxf(acc[mf][nf][1] + bb1, 0.f);
            float v2 = fmaxf(acc[mf][nf][2] + bb2v, 0.f);
            float v3 = fmaxf(acc[mf][nf][3] + bb3, 0.f);
            if (valid) {
                zb[(size_t)(obase + 0) * HW + n] = v0;
                zb[(size_t)(obase + 1) * HW + n] = v1;
                zb[(size_t)(obase + 2) * HW + n] = v2;
                zb[(size_t)(obase + 3) * HW + n] = v3;
                rmax[0] = fmaxf(rmax[0], v0);
                rmax[1] = fmaxf(rmax[1], v1);
                rmax[2] = fmaxf(rmax[2], v2);
                rmax[3] = fmaxf(rmax[3], v3);
            }
        }
#pragma unroll
        for (int r = 0; r < 4; ++r) {
            float v = rmax[r];
            v = fmaxf(v, __shfl_xor(v, 1, 64));
            v = fmaxf(v, __shfl_xor(v, 2, 64));
            v = fmaxf(v, __shfl_xor(v, 4, 64));
            v = fmaxf(v, __shfl_xor(v, 8, 64));
            if (l15 == 0)
                atomicMax(&pwmax[b * COUT + obase + r], __float_as_uint(v));
        }
    }
}

// ---------------- K3: apply pointwise cut ---------------------------------
__global__ __launch_bounds__(256) void cut_kernel(const unsigned* __restrict__ pwmax,
                                                  float* __restrict__ z) {
    int base = blockIdx.x * 8;
#pragma unroll
    for (int j = 0; j < 8; ++j) {
        int bo = base + j;
        if (__uint_as_float(pwmax[bo]) >= 1e-3f) continue;
        float4* zp = (float4*)(z + (size_t)bo * HW);
        for (int i = threadIdx.x; i < HW / 4; i += 256)
            zp[i] = make_float4(0.f, 0.f, 0.f, 0.f);
    }
}

extern "C" void kernel_launch(void* const* d_in, const int* in_sizes, int n_in,
                              void* d_out, int out_size, void* d_ws, size_t ws_size,
                              hipStream_t stream) {
    const float* x   = (const float*)d_in[0];
    const float* dww = (const float*)d_in[1];
    const float* dwb = (const float*)d_in[2];
    const float* g1  = (const float*)d_in[3];
    const float* be1 = (const float*)d_in[4];
    const float* mu1 = (const float*)d_in[5];
    const float* va1 = (const float*)d_in[6];
    const float* pww = (const float*)d_in[7];
    const float* pwb = (const float*)d_in[8];
    const float* g2  = (const float*)d_in[9];
    const float* be2 = (const float*)d_in[10];
    const float* mu2 = (const float*)d_in[11];
    const float* va2 = (const float*)d_in[12];
    float* z = (float*)d_out;

    char* ws = (char*)d_ws;
    const size_t Y_BYTES = (size_t)BATCH * CIN * NPAD * 2;  // 52,428,800
    unsigned short* y  = (unsigned short*)ws;
    unsigned short* Wp = (unsigned short*)(ws + Y_BYTES);
    float* b2          = (float*)(ws + Y_BYTES + 131072);
    unsigned* pwmax    = (unsigned*)(ws + Y_BYTES + 131072 + 1024);
    float* dwmax       = (float*)(ws + Y_BYTES + 131072 + 1024 + 32768);

    prep_kernel<<<256, 256, 0, stream>>>(pww, pwb, g2, be2, mu2, va2, Wp, b2, pwmax);
    dw_kernel<<<2048, 256, 0, stream>>>(x, dww, dwb, g1, be1, mu1, va1, y, dwmax);
    pw_kernel<<<1600, 256, 0, stream>>>(y, Wp, b2, dwmax, z, pwmax);
    cut_kernel<<<BATCH * COUT / 8, 256, 0, stream>>>(pwmax, z);
}